// Round 3
// baseline (108.884 us; speedup 1.0000x reference)
//
#include <hip/hip_runtime.h>
#include <hip/hip_bf16.h>

typedef unsigned short u16;
typedef __bf16 bf16x8 __attribute__((ext_vector_type(8)));
typedef float f32x4 __attribute__((ext_vector_type(4)));

// ---- helpers: manual bf16 <-> f32 (round-to-nearest-even), avoids header API drift ----
__device__ __forceinline__ u16 f2bf(float f) {
    unsigned u = __float_as_uint(f);
    u = u + 0x7fffu + ((u >> 16) & 1u);   // RNE
    return (u16)(u >> 16);
}

// =====================================================================================
// K0: fp32 -> bf16 convert (vectorized x4)
// =====================================================================================
__global__ __launch_bounds__(256) void k_convert(const float* __restrict__ src,
                                                 u16* __restrict__ dst, int n4) {
    int i = blockIdx.x * blockDim.x + threadIdx.x;
    if (i >= n4) return;
    float4 v = reinterpret_cast<const float4*>(src)[i];
    ushort4 o;
    o.x = f2bf(v.x); o.y = f2bf(v.y); o.z = f2bf(v.z); o.w = f2bf(v.w);
    reinterpret_cast<ushort4*>(dst)[i] = o;
}

// =====================================================================================
// K1: gather + mean (bf16 reads, fp32 accumulate, bf16 means out)
// block = 256 threads handles 2 nodes; thread covers a bf16x2 (4B) of the 256-dim row
// =====================================================================================
__global__ __launch_bounds__(256) void k_gather_mean(const int* __restrict__ nbrs,
        const unsigned* __restrict__ embu,   // [n_nodes][128] bf16x2 words
        unsigned* __restrict__ meansu,       // [m_pad][128]
        int n_nodes) {
    __shared__ int snbr[32];
    int t = threadIdx.x;
    int node = 2 * blockIdx.x + (t >> 7);
    int d2 = t & 127;
    if (t < 32) {
        int nn = 2 * blockIdx.x + (t >> 4);
        snbr[t] = (nn < n_nodes) ? nbrs[nn * 16 + (t & 15)] : 0;
    }
    __syncthreads();
    float sx = 0.f, sy = 0.f;
    if (node < n_nodes) {
        int base = (t >> 7) * 16;
        #pragma unroll
        for (int j = 0; j < 16; ++j) {
            unsigned u = embu[snbr[base + j] * 128 + d2];
            sx += __uint_as_float(u << 16);            // low bf16
            sy += __uint_as_float(u & 0xffff0000u);    // high bf16
        }
        sx *= 0.0625f; sy *= 0.0625f;
    }
    // pad rows (node >= n_nodes) get zeros -> deterministic ws contents
    unsigned lo = f2bf(sx), hi = f2bf(sy);
    meansu[node * 128 + d2] = lo | (hi << 16);
}

// =====================================================================================
// K2: y = relu(means @ W^T), row-L2-normalize, fp32 out
// block = 256 thr (4 waves), block tile = 64 rows x 256 cols; wave tile = 64 x 64
// mfma_f32_16x16x32_bf16; A row-frag and B col-frag both = contiguous 8 bf16 along K
// =====================================================================================
__global__ __launch_bounds__(256) void k_gemm_norm(
        const u16* __restrict__ means,   // [m_pad][256] bf16
        const u16* __restrict__ wbf,     // [256][256] bf16, row = out_dim, col = k
        float* __restrict__ out, int n_nodes) {
    int tid  = threadIdx.x;
    int lane = tid & 63;
    int w    = tid >> 6;              // wave 0..3 -> col block
    int r0   = blockIdx.x * 64;
    int c0   = w * 64;
    int l15  = lane & 15;
    int lg   = lane >> 4;             // 0..3 selects k-subblock of 8

    const bf16x8* A8 = reinterpret_cast<const bf16x8*>(means);
    const bf16x8* B8 = reinterpret_cast<const bf16x8*>(wbf);

    f32x4 acc[4][4];
    #pragma unroll
    for (int mt = 0; mt < 4; ++mt)
        #pragma unroll
        for (int nt = 0; nt < 4; ++nt)
            acc[mt][nt] = (f32x4){0.f, 0.f, 0.f, 0.f};

    #pragma unroll
    for (int kt = 0; kt < 8; ++kt) {       // K = 256 = 8 * 32
        bf16x8 a[4], b[4];
        #pragma unroll
        for (int mt = 0; mt < 4; ++mt)
            a[mt] = A8[(r0 + mt * 16 + l15) * 32 + kt * 4 + lg];
        #pragma unroll
        for (int nt = 0; nt < 4; ++nt)
            b[nt] = B8[(c0 + nt * 16 + l15) * 32 + kt * 4 + lg];
        #pragma unroll
        for (int mt = 0; mt < 4; ++mt)
            #pragma unroll
            for (int nt = 0; nt < 4; ++nt)
                acc[mt][nt] = __builtin_amdgcn_mfma_f32_16x16x32_bf16(
                                  a[mt], b[nt], acc[mt][nt], 0, 0, 0);
    }

    // relu + per-row partial sum of squares (this wave covers 64 of 256 cols)
    // C layout (verified, guide m89): reg j of lane -> row=(lane>>4)*4+j, col=lane&15
    float p[4][4];
    #pragma unroll
    for (int mt = 0; mt < 4; ++mt)
        #pragma unroll
        for (int j = 0; j < 4; ++j) {
            float s = 0.f;
            #pragma unroll
            for (int nt = 0; nt < 4; ++nt) {
                float v = fmaxf(acc[mt][nt][j], 0.f);
                acc[mt][nt][j] = v;
                s += v * v;
            }
            p[mt][j] = s;
        }
    // butterfly over low-4 lane bits (16 cols per tile)
    #pragma unroll
    for (int m = 1; m < 16; m <<= 1)
        #pragma unroll
        for (int mt = 0; mt < 4; ++mt)
            #pragma unroll
            for (int j = 0; j < 4; ++j)
                p[mt][j] += __shfl_xor(p[mt][j], m, 64);

    __shared__ float ssq[4][64];
    __shared__ float inv[64];
    if (l15 == 0) {
        #pragma unroll
        for (int mt = 0; mt < 4; ++mt)
            #pragma unroll
            for (int j = 0; j < 4; ++j)
                ssq[w][mt * 16 + lg * 4 + j] = p[mt][j];
    }
    __syncthreads();
    if (tid < 64) {
        float s = ssq[0][tid] + ssq[1][tid] + ssq[2][tid] + ssq[3][tid];
        inv[tid] = 1.f / fmaxf(sqrtf(s), 1e-12f);
    }
    __syncthreads();

    #pragma unroll
    for (int mt = 0; mt < 4; ++mt) {
        int rloc = mt * 16 + lg * 4;
        #pragma unroll
        for (int j = 0; j < 4; ++j) {
            int row = r0 + rloc + j;
            if (row < n_nodes) {
                float iv = inv[rloc + j];
                #pragma unroll
                for (int nt = 0; nt < 4; ++nt)
                    out[row * 256 + c0 + nt * 16 + l15] = acc[mt][nt][j] * iv;
            }
        }
    }
}

// =====================================================================================
// Fallback (only if ws is too small): fully fused fp32, one block per node
// =====================================================================================
__global__ __launch_bounds__(256) void k_fused_fallback(const int* __restrict__ nbrs,
        const float* __restrict__ emb, const float* __restrict__ W,
        float* __restrict__ out, int n_nodes) {
    __shared__ __align__(16) float h[256];
    __shared__ int sn[16];
    __shared__ float sred[4];
    int i = blockIdx.x;
    int t = threadIdx.x;
    if (t < 16) sn[t] = nbrs[i * 16 + t];
    __syncthreads();
    float s = 0.f;
    #pragma unroll
    for (int j = 0; j < 16; ++j) s += emb[sn[j] * 256 + t];
    h[t] = s * 0.0625f;
    __syncthreads();
    const float4* W4 = reinterpret_cast<const float4*>(W);
    const float4* h4 = reinterpret_cast<const float4*>(h);
    float y = 0.f;
    #pragma unroll 8
    for (int k4 = 0; k4 < 64; ++k4) {
        float4 wv = W4[t * 64 + k4];
        float4 hv = h4[k4];
        y += wv.x * hv.x + wv.y * hv.y + wv.z * hv.z + wv.w * hv.w;
    }
    y = fmaxf(y, 0.f);
    float q = y * y;
    #pragma unroll
    for (int m = 1; m < 64; m <<= 1) q += __shfl_xor(q, m, 64);
    if ((t & 63) == 0) sred[t >> 6] = q;
    __syncthreads();
    float tot = sred[0] + sred[1] + sred[2] + sred[3];
    out[i * 256 + t] = y * (1.f / fmaxf(sqrtf(tot), 1e-12f));
}

extern "C" void kernel_launch(void* const* d_in, const int* in_sizes, int n_in,
                              void* d_out, int out_size, void* d_ws, size_t ws_size,
                              hipStream_t stream) {
    const int*   nbrs = (const int*)d_in[0];     // [n_nodes, 16] int32
    const float* emb  = (const float*)d_in[1];   // [n_nodes, 256] f32
    const float* W    = (const float*)d_in[2];   // [256, 256] f32 (out, in)
    float* out = (float*)d_out;

    const int degree = 16, dim = 256;
    const int n_nodes = in_sizes[0] / degree;            // 50000
    const int m_pad   = (n_nodes + 63) & ~63;            // 50048

    // ws layout (256B-aligned sections)
    size_t off_emb   = 0;
    size_t sz_emb    = (size_t)n_nodes * dim * 2;                       // bf16 emb
    size_t off_w     = (off_emb + sz_emb + 255) & ~(size_t)255;
    size_t sz_w      = (size_t)dim * dim * 2;                           // bf16 W
    size_t off_means = (off_w + sz_w + 255) & ~(size_t)255;
    size_t sz_means  = (size_t)m_pad * dim * 2;                         // bf16 means
    size_t need      = off_means + sz_means;

    if (ws_size < need) {
        // insurance path: correct but slow
        k_fused_fallback<<<n_nodes, 256, 0, stream>>>(nbrs, emb, W, out, n_nodes);
        return;
    }

    char* ws = (char*)d_ws;
    u16* emb_bf = (u16*)(ws + off_emb);
    u16* w_bf   = (u16*)(ws + off_w);
    u16* means  = (u16*)(ws + off_means);

    int n4e = n_nodes * dim / 4;       // 3,200,000
    int n4w = dim * dim / 4;           // 16,384
    k_convert<<<(n4e + 255) / 256, 256, 0, stream>>>(emb, emb_bf, n4e);
    k_convert<<<(n4w + 255) / 256, 256, 0, stream>>>(W, w_bf, n4w);
    k_gather_mean<<<m_pad / 2, 256, 0, stream>>>(nbrs, (const unsigned*)emb_bf,
                                                 (unsigned*)means, n_nodes);
    k_gemm_norm<<<m_pad / 64, 256, 0, stream>>>(means, w_bf, out, n_nodes);
}